// Round 8
// baseline (828.123 us; speedup 1.0000x reference)
//
#include <hip/hip_runtime.h>
#include <hip/hip_cooperative_groups.h>
#include <hip/hip_bf16.h>

namespace cg = cooperative_groups;

#define N0 100000
#define N1 50000
#define N2 20000
#define DD 128
#define E0 600000
#define E1 300000

#define NSEG_TOT (2 * N1 + 2 * N2)              // 140000 concat CSR segments
#define ETOT     (2 * E0 + 2 * E1)              // 1800000 edges

// counting-sort geometry
#define SEG_SHIFT 9                              // 512 segments per bucket
#define NBK  ((NSEG_TOT + 511) / 512)            // 274 buckets
#define NBK_PAD 288
#define CH   2048                                // edges per chunk
#define NCH  ((ETOT + CH - 1) / CH)              // 879 chunks

#define COOP_GRID 1024                           // 4 blocks/CU guaranteed co-resident

// fused layer kernel geometry
#define LNODES 64                                // nodes per block
#define LROWS  (2 * LNODES)                      // 2 relations
#define LSTRIDE 152                              // bf16 elems per LDS row (304 B, 16B-mult)

typedef __attribute__((ext_vector_type(8))) short short8;   // 8 bf16 (4 VGPRs)
typedef __attribute__((ext_vector_type(4))) float floatx4;  // MFMA acc

__device__ __forceinline__ void st2bf(__hip_bfloat16* p, float a, float b) {
    __hip_bfloat162 v;
    v.x = __float2bfloat16(a);
    v.y = __float2bfloat16(b);
    *(__hip_bfloat162*)p = v;
}
__device__ __forceinline__ short bf16bits(float v) {
    __hip_bfloat16 b = __float2bfloat16(v);
    return *(short*)&b;
}
__device__ __forceinline__ float bf2f(unsigned short u) {
    return __uint_as_float(((unsigned int)u) << 16);
}
__device__ __forceinline__ float4 ld4bf(const __hip_bfloat16* p) {  // 8B load
    ushort4 u = *(const ushort4*)p;
    return make_float4(bf2f(u.x), bf2f(u.y), bf2f(u.z), bf2f(u.w));
}
__device__ __forceinline__ void st4bf(__hip_bfloat16* p, float4 v) { // 8B store
    short vs[4];
    vs[0] = bf16bits(v.x); vs[1] = bf16bits(v.y);
    vs[2] = bf16bits(v.z); vs[3] = bf16bits(v.w);
    *(int2*)p = *(int2*)vs;
}

// inclusive Hillis-Steele scan over 256 threads; every thread must call.
__device__ __forceinline__ int scan256(int s, int* sh, int t) {
    sh[t] = s;
    __syncthreads();
    for (int off = 1; off < 256; off <<= 1) {
        int tmp = (t >= off) ? sh[t - off] : 0;
        __syncthreads();
        sh[t] += tmp;
        __syncthreads();
    }
    return sh[t];
}

// Edge mapping for the concatenated CSR (4 edge lists):
//   [0,E0)->L1r0 base 0; [E0,2E0)->L1r1 base N1;
//   [2E0,2E0+E1)->L2r0 base 2N1; rest->L2r1 base 2N1+N2
__device__ __forceinline__ int edge_seg(int e,
    const int* d0, const int* d1, const int* d2, const int* d3)
{
    if (e < E0)               return d0[e];
    if (e < 2 * E0)           return N1 + d1[e - E0];
    if (e < 2 * E0 + E1)      return 2 * N1 + d2[e - 2 * E0];
    return 2 * N1 + N2 + d3[e - 2 * E0 - E1];
}
__device__ __forceinline__ int2 edge_seg_src(int e,
    const int* s0, const int* d0, const int* s1, const int* d1,
    const int* s2, const int* d2, const int* s3, const int* d3)
{
    if (e < E0)               return make_int2(s0[e],            d0[e]);
    if (e < 2 * E0)           return make_int2(s1[e - E0],       N1 + d1[e - E0]);
    if (e < 2 * E0 + E1)      return make_int2(s2[e - 2 * E0],   2 * N1 + d2[e - 2 * E0]);
    int ee = e - 2 * E0 - E1;
    return make_int2(s3[ee], 2 * N1 + N2 + d3[ee]);
}

// builds basel[0..512): exclusive scan of tot (entries >= NBK add 0)
__device__ __forceinline__ void build_base(const int* tot, int* basel, int* sh, int t)
{
    int l0 = 2 * t, l1 = 2 * t + 1;
    int v0 = (l0 < NBK) ? tot[l0] : 0;
    int v1 = (l1 < NBK) ? tot[l1] : 0;
    int s = v0 + v1;
    int incl = scan256(s, sh, t);
    int ex = incl - s;
    basel[l0] = ex;
    basel[l1] = ex + v0;
}

// ---------------------------------------------------------------------------
// Cooperative CSR-build kernel: all phases in one launch, grid.sync between.
//   A: cast x->xb  |  weight-prep both layers  |  per-chunk bucket histogram
//   B: per-bucket exclusive scan across chunks
//   C: bucket-grouped (src,seg) record scatter (LDS cursors)
//   D: per-bucket CSR finalize (LDS hist+scan -> row_ptr, eidx)
// No global atomics anywhere.
// ---------------------------------------------------------------------------
struct CsrArgs {
    const float* x; __hip_bfloat16* xb;
    const int* s0a; const int* d0a; const int* s0b; const int* d0b;
    const int* s1a; const int* d1a; const int* s1b; const int* d1b;
    int* cntmat; int* pre; int* tot; int2* ebuf; int* row_ptr; int* eidx;
    const float* Ws1a; const float* Ws1b; const float* Wn1a; const float* Wn1b;
    const float* Ws2a; const float* Ws2b; const float* Wn2a; const float* Wn2b;
    short* wfrag1; short* wfrag2;
};

__global__ __launch_bounds__(256, 4) void coop_csr_kernel(CsrArgs a)
{
    cg::grid_group grid = cg::this_grid();
    __shared__ int sh[256];
    __shared__ int basel[512];
    __shared__ int hist[512];     // also cur / cnt
    __shared__ int excl[512];
    const int t = threadIdx.x;
    const int nthr = gridDim.x * 256;
    const int gtid = blockIdx.x * 256 + t;

    // ---- Phase A1: cast (grid-stride over 3.2M float4) ----
    for (int i = gtid; i < N0 * DD / 4; i += nthr) {
        float4 v = ((const float4*)a.x)[i];
        st2bf(a.xb + (size_t)i * 4, v.x, v.y);
        st2bf(a.xb + (size_t)i * 4 + 2, v.z, v.w);
    }
    // ---- Phase A2: weight prep (both layers, 12288 lanes of work) ----
    for (int p = gtid; p < 2 * 6144; p += nthr) {
        int layer = p >= 6144;
        int q = p - layer * 6144;
        int lane = q & 63;
        int mt = (q >> 6) & 7;
        int kc = q >> 9;
        int n = mt * 16 + (lane & 15);
        int k0 = kc * 32 + ((lane >> 4) << 3);
        const float* Wsa = layer ? a.Ws2a : a.Ws1a;
        const float* Wsb = layer ? a.Ws2b : a.Ws1b;
        const float* Wna = layer ? a.Wn2a : a.Wn1a;
        const float* Wnb = layer ? a.Wn2b : a.Wn1b;
        short* wf = layer ? a.wfrag2 : a.wfrag1;
        short vals[8];
#pragma unroll
        for (int j = 0; j < 8; j++) {
            int k = k0 + j;
            float w;
            if (k < 128)      w = Wsa[k * DD + n] + Wsb[k * DD + n];
            else if (k < 256) w = Wna[(k - 128) * DD + n];
            else              w = Wnb[(k - 256) * DD + n];
            vals[j] = bf16bits(w);
        }
        *(short8*)(wf + (size_t)q * 8) = *(short8*)vals;
    }
    // ---- Phase A3: per-chunk bucket histogram ----
    for (int chunk = blockIdx.x; chunk < NCH; chunk += gridDim.x) {
        for (int l = t; l < NBK_PAD; l += 256) hist[l] = 0;
        __syncthreads();
#pragma unroll
        for (int it = 0; it < CH / 256; it++) {
            int e = chunk * CH + it * 256 + t;
            if (e < ETOT) {
                int seg = edge_seg(e, a.d0a, a.d0b, a.d1a, a.d1b);
                atomicAdd(&hist[seg >> SEG_SHIFT], 1);         // LDS atomic
            }
        }
        __syncthreads();
        for (int g = t; g < NBK; g += 256)
            a.cntmat[(size_t)g * NCH + chunk] = hist[g];
        __syncthreads();
    }
    grid.sync();

    // ---- Phase B: per-bucket exclusive scan across chunks ----
    for (int g = blockIdx.x; g < NBK; g += gridDim.x) {
        const size_t roff = (size_t)g * NCH;
        int v[4]; int s = 0;
#pragma unroll
        for (int i = 0; i < 4; i++) {
            int idx = t * 4 + i;
            v[i] = (idx < NCH) ? a.cntmat[roff + idx] : 0;
            s += v[i];
        }
        int incl = scan256(s, sh, t);
        int ex = incl - s;
#pragma unroll
        for (int i = 0; i < 4; i++) {
            int idx = t * 4 + i;
            if (idx < NCH) a.pre[roff + idx] = ex;
            ex += v[i];
        }
        if (t == 255) a.tot[g] = incl;
        __syncthreads();
    }
    grid.sync();

    // ---- Phase C: bucket-grouped record scatter ----
    build_base(a.tot, basel, sh, t);
    __syncthreads();
    for (int chunk = blockIdx.x; chunk < NCH; chunk += gridDim.x) {
        for (int l = t; l < NBK_PAD; l += 256) hist[l] = 0;    // cursors
        __syncthreads();
#pragma unroll
        for (int it = 0; it < CH / 256; it++) {
            int e = chunk * CH + it * 256 + t;
            if (e < ETOT) {
                int2 r = edge_seg_src(e, a.s0a, a.d0a, a.s0b, a.d0b,
                                         a.s1a, a.d1a, a.s1b, a.d1b);
                int g = r.y >> SEG_SHIFT;
                int rk = atomicAdd(&hist[g], 1);               // LDS atomic
                a.ebuf[basel[g] + a.pre[(size_t)g * NCH + chunk] + rk] = r;
            }
        }
        __syncthreads();
    }
    grid.sync();

    // ---- Phase D: per-bucket CSR finalize ----
    const int l0 = 2 * t, l1 = 2 * t + 1;
    for (int g = blockIdx.x; g < NBK; g += gridDim.x) {
        hist[l0] = 0; hist[l1] = 0;                            // cnt
        __syncthreads();
        const int b0 = basel[g];
        const int b1 = basel[g + 1];                           // g+1 <= NBK < 512
        const int Eloc = b1 - b0;
        const int segbase = g << SEG_SHIFT;

        for (int i = t; i < Eloc; i += 256) {
            int2 rec = a.ebuf[b0 + i];
            atomicAdd(&hist[rec.y - segbase], 1);              // LDS atomic
        }
        __syncthreads();

        int c0 = hist[l0], c1 = hist[l1];
        int ssum = c0 + c1;
        int inc2 = scan256(ssum, sh, t);
        int ex2 = inc2 - ssum;
        excl[l0] = ex2;
        excl[l1] = ex2 + c0;
        __syncthreads();

        int nloc = NSEG_TOT - segbase;
        if (nloc > 512) nloc = 512;
        for (int l = t; l < nloc; l += 256) a.row_ptr[segbase + l] = b0 + excl[l];
        if (g == 0 && t == 0) a.row_ptr[NSEG_TOT] = ETOT;

        hist[l0] = 0; hist[l1] = 0;                            // cursors
        __syncthreads();

        for (int i = t; i < Eloc; i += 256) {
            int2 rec = a.ebuf[b0 + i];
            int l = rec.y - segbase;
            int r = atomicAdd(&hist[l], 1);
            a.eidx[b0 + excl[l] + r] = rec.x;                  // bucket-local, L2-hot
        }
        __syncthreads();
    }
}

// ---------------------------------------------------------------------------
// Fused layer: per block of 64 nodes:
//   Phase 1: 4 waves aggregate the block's own 128 CSR segments (2 rels x 64
//            nodes) into LDS (one wave per segment, half-wave row pairs).
//   Phase 2: MFMA combine, neighbor B-frags read from LDS, self from global.
// ---------------------------------------------------------------------------
template <bool RELU, typename TOUT>
__global__ __launch_bounds__(256) void fused_layer_kernel(
    const __hip_bfloat16* __restrict__ xsrc,   // [M][128] self + gather table
    const int* __restrict__ row_ptr,           // this layer's 2M+1 CSR rows
    const int* __restrict__ eidx,              // absolute positions
    const short* __restrict__ wfrag,           // 12*8*64*8 bf16 bits
    const float* __restrict__ b0, const float* __restrict__ b1,
    TOUT* __restrict__ out, int M)
{
    __shared__ __align__(16) short lhn[LROWS * LSTRIDE];
    const int t = threadIdx.x;
    const int wave = t >> 6;
    const int lane = t & 63;
    const int nb0 = blockIdx.x * LNODES;

    // ---- Phase 1: aggregate into LDS ----
    const int half = lane >> 5;
    const int l32 = lane & 31;
    for (int li = wave * 32; li < wave * 32 + 32; li++) {
        int rel = li >> 6;
        int node = nb0 + (li & 63);
        float4 s = make_float4(0.f, 0.f, 0.f, 0.f);
        int cnt = 0;
        if (node < M) {
            int seg = rel * M + node;
            int beg = row_ptr[seg];
            int end = row_ptr[seg + 1];
            cnt = end - beg;
            int k = beg;
            for (; k + 4 <= end; k += 4) {
                int i0 = eidx[k + 0];
                int i1 = eidx[k + 1];
                int i2 = eidx[k + 2];
                int i3 = eidx[k + 3];
                int ra = half ? i1 : i0;
                int rb = half ? i3 : i2;
                float4 va = ld4bf(xsrc + (long)ra * DD + l32 * 4);
                float4 vb = ld4bf(xsrc + (long)rb * DD + l32 * 4);
                s.x += va.x + vb.x; s.y += va.y + vb.y;
                s.z += va.z + vb.z; s.w += va.w + vb.w;
            }
            if (k + 2 <= end) {
                int i0 = eidx[k];
                int i1 = eidx[k + 1];
                int r = half ? i1 : i0;
                float4 v = ld4bf(xsrc + (long)r * DD + l32 * 4);
                s.x += v.x; s.y += v.y; s.z += v.z; s.w += v.w;
                k += 2;
            }
            if (k < end && !half) {
                int i0 = eidx[k];
                float4 v = ld4bf(xsrc + (long)i0 * DD + l32 * 4);
                s.x += v.x; s.y += v.y; s.z += v.z; s.w += v.w;
            }
        }
        s.x += __shfl_xor(s.x, 32);
        s.y += __shfl_xor(s.y, 32);
        s.z += __shfl_xor(s.z, 32);
        s.w += __shfl_xor(s.w, 32);
        if (!half) {
            const float inv = 1.f / (float)(cnt > 1 ? cnt : 1);
            st4bf((__hip_bfloat16*)&lhn[li * LSTRIDE + l32 * 4],
                  make_float4(s.x * inv, s.y * inv, s.z * inv, s.w * inv));
        }
    }
    __syncthreads();

    // ---- Phase 2: MFMA combine ----
    const int nsub = lane & 15;
    const int quad = lane >> 4;
    const int lnode = wave * 16 + nsub;        // local node in [0,64)
    const int node = nb0 + lnode;
    const long nc = node < M ? node : M - 1;   // clamp for global self loads

    floatx4 acc[8];
#pragma unroll
    for (int mt = 0; mt < 8; mt++) acc[mt] = (floatx4){0.f, 0.f, 0.f, 0.f};

    for (int kc = 0; kc < 12; kc++) {
        short8 bf;
        if (kc < 4) {
            bf = *(const short8*)(xsrc + nc * DD + kc * 32 + quad * 8);
        } else {
            int rel = (kc >= 8);
            int koff = (kc - 4 - rel * 4) * 32;
            int li = rel * LNODES + lnode;
            bf = *(const short8*)(lhn + li * LSTRIDE + koff + quad * 8);
        }
        const short* wbase = wfrag + ((size_t)(kc * 8) * 64 + lane) * 8;
#pragma unroll
        for (int mt = 0; mt < 8; mt++) {
            short8 af = *(const short8*)(wbase + (size_t)mt * 64 * 8);
            acc[mt] = __builtin_amdgcn_mfma_f32_16x16x32_bf16(af, bf, acc[mt], 0, 0, 0);
        }
    }

    if (node < M) {
#pragma unroll
        for (int mt = 0; mt < 8; mt++) {
            int c0 = mt * 16 + quad * 4;
            float4 bb0 = *(const float4*)(b0 + c0);
            float4 bb1 = *(const float4*)(b1 + c0);
            float v0 = acc[mt][0] + bb0.x + bb1.x;
            float v1 = acc[mt][1] + bb0.y + bb1.y;
            float v2 = acc[mt][2] + bb0.z + bb1.z;
            float v3 = acc[mt][3] + bb0.w + bb1.w;
            if (RELU) {
                v0 = v0 > 0.f ? v0 : 0.f;
                v1 = v1 > 0.f ? v1 : 0.f;
                v2 = v2 > 0.f ? v2 : 0.f;
                v3 = v3 > 0.f ? v3 : 0.f;
            }
            TOUT* p = out + (long)node * DD + c0;
            if constexpr (sizeof(TOUT) == 4) {
                *(float4*)p = make_float4(v0, v1, v2, v3);
            } else {
                short vs[4];
                vs[0] = bf16bits(v0); vs[1] = bf16bits(v1);
                vs[2] = bf16bits(v2); vs[3] = bf16bits(v3);
                *(int2*)p = *(int2*)vs;
            }
        }
    }
}

// ---------------------------------------------------------------------------

extern "C" void kernel_launch(void* const* d_in, const int* in_sizes, int n_in,
                              void* d_out, int out_size, void* d_ws, size_t ws_size,
                              hipStream_t stream)
{
    const float* x = (const float*)d_in[0];
    const int* e0_src_r0 = (const int*)d_in[1];
    const int* e0_dst_r0 = (const int*)d_in[2];
    const int* e0_src_r1 = (const int*)d_in[3];
    const int* e0_dst_r1 = (const int*)d_in[4];
    const int* e1_src_r0 = (const int*)d_in[5];
    const int* e1_dst_r0 = (const int*)d_in[6];
    const int* e1_src_r1 = (const int*)d_in[7];
    const int* e1_dst_r1 = (const int*)d_in[8];
    const float* Ws1_r0 = (const float*)d_in[9];
    const float* Wn1_r0 = (const float*)d_in[10];
    const float* Ws1_r1 = (const float*)d_in[11];
    const float* Wn1_r1 = (const float*)d_in[12];
    const float* Ws2_r0 = (const float*)d_in[13];
    const float* Wn2_r0 = (const float*)d_in[14];
    const float* Ws2_r1 = (const float*)d_in[15];
    const float* Wn2_r1 = (const float*)d_in[16];
    const float* b1_r0 = (const float*)d_in[17];
    const float* b1_r1 = (const float*)d_in[18];
    const float* b2_r0 = (const float*)d_in[19];
    const float* b2_r1 = (const float*)d_in[20];
    float* out = (float*)d_out;

    // Workspace (~62.7 MB; h1 no longer aliases xb — agg+combine now share a
    // dispatch, so xb must stay intact until fused1 finishes):
    //   xb      : N0*DD bf16 (25.6 MB)
    //   h1      : N1*DD bf16 (12.8 MB)
    //   ebuf    : ETOT int2 (14.4 MB)
    //   eidx    : ETOT int (7.2 MB)
    //   row_ptr : NSEG_TOT+4 int
    //   cntmat  : NBK*NCH int (963 KB)
    //   pre     : NBK*NCH int (963 KB)
    //   tot     : NBK+4 int
    //   wfrag1/2: 2 x 49152 bf16 (192 KB)
    __hip_bfloat16* xb = (__hip_bfloat16*)d_ws;
    __hip_bfloat16* h1 = xb + (size_t)N0 * DD;
    int2* ebuf    = (int2*)(h1 + (size_t)N1 * DD);
    int* eidx     = (int*)(ebuf + ETOT);
    int* row_ptr  = eidx + ETOT;
    int* cntmat   = row_ptr + NSEG_TOT + 4;
    int* pre      = cntmat + NBK * NCH;
    int* tot      = pre + NBK * NCH;
    short* wfrag1 = (short*)(tot + NBK + 4);
    short* wfrag2 = wfrag1 + 12 * 8 * 64 * 8;

    // 1. cooperative CSR build (cast | prep | count -> scan -> scatter -> finalize)
    CsrArgs ca;
    ca.x = x; ca.xb = xb;
    ca.s0a = e0_src_r0; ca.d0a = e0_dst_r0; ca.s0b = e0_src_r1; ca.d0b = e0_dst_r1;
    ca.s1a = e1_src_r0; ca.d1a = e1_dst_r0; ca.s1b = e1_src_r1; ca.d1b = e1_dst_r1;
    ca.cntmat = cntmat; ca.pre = pre; ca.tot = tot; ca.ebuf = ebuf;
    ca.row_ptr = row_ptr; ca.eidx = eidx;
    ca.Ws1a = Ws1_r0; ca.Ws1b = Ws1_r1; ca.Wn1a = Wn1_r0; ca.Wn1b = Wn1_r1;
    ca.Ws2a = Ws2_r0; ca.Ws2b = Ws2_r1; ca.Wn2a = Wn2_r0; ca.Wn2b = Wn2_r1;
    ca.wfrag1 = wfrag1; ca.wfrag2 = wfrag2;
    void* args[] = { &ca };
    hipLaunchCooperativeKernel((const void*)coop_csr_kernel,
                               dim3(COOP_GRID), dim3(256), args, 0, stream);

    // 2. fused layer 1: aggregate + combine -> h1 (bf16), ReLU
    fused_layer_kernel<true, __hip_bfloat16>
        <<<(N1 + LNODES - 1) / LNODES, 256, 0, stream>>>(
            xb, row_ptr, eidx, wfrag1, b1_r0, b1_r1, h1, N1);

    // 3. fused layer 2: aggregate + combine -> out (fp32)
    fused_layer_kernel<false, float>
        <<<(N2 + LNODES - 1) / LNODES, 256, 0, stream>>>(
            h1, row_ptr + 2 * N1, eidx, wfrag2, b2_r0, b2_r1, out, N2);
}

// Round 9
// 282.902 us; speedup vs baseline: 2.9272x; 2.9272x over previous
//
#include <hip/hip_runtime.h>
#include <hip/hip_bf16.h>

#define N0 100000
#define N1 50000
#define N2 20000
#define DD 128
#define E0 600000
#define E1 300000

#define NSEG_TOT (2 * N1 + 2 * N2)              // 140000 concat CSR segments
#define ETOT     (2 * E0 + 2 * E1)              // 1800000 edges

// counting-sort geometry
#define SEG_SHIFT 9                              // 512 segments per bucket
#define NBK  ((NSEG_TOT + 511) / 512)            // 274 buckets
#define CH   2048                                // edges per chunk
#define NCH  ((ETOT + CH - 1) / CH)              // 879 chunks
#define CAP_REC 8192                             // finalize LDS record capacity

#define CAST_BLOCKS 12500                        // N0*DD/4 / 256
#define PREP_BLOCKS 48                           // 2*6144/256
#define PROLOGUE_BLOCKS (CAST_BLOCKS + PREP_BLOCKS + NCH)

typedef __attribute__((ext_vector_type(8))) short short8;   // 8 bf16 (4 VGPRs)
typedef __attribute__((ext_vector_type(4))) float floatx4;  // MFMA acc

__device__ __forceinline__ void st2bf(__hip_bfloat16* p, float a, float b) {
    __hip_bfloat162 v;
    v.x = __float2bfloat16(a);
    v.y = __float2bfloat16(b);
    *(__hip_bfloat162*)p = v;
}
__device__ __forceinline__ short bf16bits(float v) {
    __hip_bfloat16 b = __float2bfloat16(v);
    return *(short*)&b;
}
__device__ __forceinline__ float bf2f(unsigned short u) {
    return __uint_as_float(((unsigned int)u) << 16);
}
__device__ __forceinline__ float4 ld4bf(const __hip_bfloat16* p) {  // 8B load
    ushort4 u = *(const ushort4*)p;
    return make_float4(bf2f(u.x), bf2f(u.y), bf2f(u.z), bf2f(u.w));
}
__device__ __forceinline__ void st4bf(__hip_bfloat16* p, float4 v) { // 8B store
    short vs[4];
    vs[0] = bf16bits(v.x); vs[1] = bf16bits(v.y);
    vs[2] = bf16bits(v.z); vs[3] = bf16bits(v.w);
    *(int2*)p = *(int2*)vs;
}

// inclusive Hillis-Steele scan over 256 threads; every thread must call.
__device__ __forceinline__ int scan256(int s, int* sh, int t) {
    sh[t] = s;
    __syncthreads();
    for (int off = 1; off < 256; off <<= 1) {
        int tmp = (t >= off) ? sh[t - off] : 0;
        __syncthreads();
        sh[t] += tmp;
        __syncthreads();
    }
    return sh[t];
}

// Edge mapping for the concatenated CSR (4 edge lists)
__device__ __forceinline__ int2 edge_seg_src(int e,
    const int* s0, const int* d0, const int* s1, const int* d1,
    const int* s2, const int* d2, const int* s3, const int* d3)
{
    if (e < E0)               return make_int2(s0[e],            d0[e]);
    if (e < 2 * E0)           return make_int2(s1[e - E0],       N1 + d1[e - E0]);
    if (e < 2 * E0 + E1)      return make_int2(s2[e - 2 * E0],   2 * N1 + d2[e - 2 * E0]);
    int ee = e - 2 * E0 - E1;
    return make_int2(s3[ee], 2 * N1 + N2 + d3[ee]);
}

// builds basel[0..512): exclusive scan of tot (entries >= NBK add 0)
__device__ __forceinline__ void build_base(const int* tot, int* basel, int* sh, int t)
{
    int l0 = 2 * t, l1 = 2 * t + 1;
    int v0 = (l0 < NBK) ? tot[l0] : 0;
    int v1 = (l1 < NBK) ? tot[l1] : 0;
    int s = v0 + v1;
    int incl = scan256(s, sh, t);
    int ex = incl - s;
    basel[l0] = ex;
    basel[l1] = ex + v0;
}

// ---------------------------------------------------------------------------
// Prologue: [cast | weight-prep | chunk-local bucket sort], by blockIdx range.
// Chunk part: LDS histogram over buckets -> LDS scan -> LDS scatter ->
// COALESCED write of bucket-sorted (src,seg) records to chunkbuf, plus
// cntmat/ofsmat (per-chunk bucket counts and in-chunk offsets).
// No global atomics anywhere.
// ---------------------------------------------------------------------------
__global__ __launch_bounds__(256) void prologue_kernel(
    const float* __restrict__ x, __hip_bfloat16* __restrict__ xb,
    const int* __restrict__ s0a, const int* __restrict__ d0a,
    const int* __restrict__ s0b, const int* __restrict__ d0b,
    const int* __restrict__ s1a, const int* __restrict__ d1a,
    const int* __restrict__ s1b, const int* __restrict__ d1b,
    int* __restrict__ cntmat, int* __restrict__ ofsmat,
    int2* __restrict__ chunkbuf,
    const float* __restrict__ Ws1a, const float* __restrict__ Ws1b,
    const float* __restrict__ Wn1a, const float* __restrict__ Wn1b,
    const float* __restrict__ Ws2a, const float* __restrict__ Ws2b,
    const float* __restrict__ Wn2a, const float* __restrict__ Wn2b,
    short* __restrict__ wfrag1, short* __restrict__ wfrag2)
{
    __shared__ int hist[512];
    __shared__ int ofs[512];
    __shared__ int sh[256];
    __shared__ int2 rec[CH];
    const int bid = blockIdx.x;
    const int t = threadIdx.x;

    if (bid < CAST_BLOCKS) {
        int i = bid * 256 + t;                          // < 3.2M exactly
        float4 v = ((const float4*)x)[i];
        st2bf(xb + (size_t)i * 4, v.x, v.y);
        st2bf(xb + (size_t)i * 4 + 2, v.z, v.w);
    } else if (bid < CAST_BLOCKS + PREP_BLOCKS) {
        int p = (bid - CAST_BLOCKS) * 256 + t;          // < 12288
        int layer = p >= 6144;
        int q = p - layer * 6144;
        int lane = q & 63;
        int mt = (q >> 6) & 7;
        int kc = q >> 9;
        int n = mt * 16 + (lane & 15);
        int k0 = kc * 32 + ((lane >> 4) << 3);
        const float* Wsa = layer ? Ws2a : Ws1a;
        const float* Wsb = layer ? Ws2b : Ws1b;
        const float* Wna = layer ? Wn2a : Wn1a;
        const float* Wnb = layer ? Wn2b : Wn1b;
        short* wf = layer ? wfrag2 : wfrag1;
        short vals[8];
#pragma unroll
        for (int j = 0; j < 8; j++) {
            int k = k0 + j;
            float w;
            if (k < 128)      w = Wsa[k * DD + n] + Wsb[k * DD + n];
            else if (k < 256) w = Wna[(k - 128) * DD + n];
            else              w = Wnb[(k - 256) * DD + n];
            vals[j] = bf16bits(w);
        }
        *(short8*)(wf + (size_t)q * 8) = *(short8*)vals;
    } else {
        const int chunk = bid - CAST_BLOCKS - PREP_BLOCKS;
        const int ebase = chunk * CH;
        const int ecount = (ETOT - ebase < CH) ? (ETOT - ebase) : CH;

        hist[t] = 0; hist[t + 256] = 0;
        __syncthreads();

        int2 myrec[CH / 256];
#pragma unroll
        for (int it = 0; it < CH / 256; it++) {
            int e = ebase + it * 256 + t;
            int2 r = make_int2(0, -1);
            if (e < ETOT) {
                r = edge_seg_src(e, s0a, d0a, s0b, d0b, s1a, d1a, s1b, d1b);
                atomicAdd(&hist[r.y >> SEG_SHIFT], 1);   // LDS atomic
            }
            myrec[it] = r;
        }
        __syncthreads();

        // exclusive scan over 512 bucket slots (2/thread)
        const int l0 = 2 * t, l1 = 2 * t + 1;
        int c0 = hist[l0], c1 = hist[l1];
        int s = c0 + c1;
        int incl = scan256(s, sh, t);
        int ex = incl - s;
        ofs[l0] = ex;
        ofs[l1] = ex + c0;
        __syncthreads();

        // write per-chunk counts and offsets (before cursors mutate ofs)
        for (int g = t; g < NBK; g += 256) {
            cntmat[(size_t)g * NCH + chunk] = hist[g];
            ofsmat[(size_t)g * NCH + chunk] = ofs[g];
        }
        __syncthreads();

        // scatter records into bucket order in LDS (ofs now cursors)
#pragma unroll
        for (int it = 0; it < CH / 256; it++) {
            int2 r = myrec[it];
            if (r.y >= 0) {
                int rk = atomicAdd(&ofs[r.y >> SEG_SHIFT], 1);  // LDS atomic
                rec[rk] = r;
            }
        }
        __syncthreads();

        // coalesced write-out
        for (int i = t; i < ecount; i += 256)
            chunkbuf[ebase + i] = rec[i];
    }
}

// ---------------------------------------------------------------------------
// Per-bucket exclusive scan across chunks; bucket totals.
// ---------------------------------------------------------------------------
__global__ __launch_bounds__(256) void scan_chunks_kernel(
    const int* __restrict__ cntmat, int* __restrict__ pre, int* __restrict__ tot)
{
    __shared__ int sh[256];
    const int t = threadIdx.x;
    const int g = blockIdx.x;
    const size_t roff = (size_t)g * NCH;
    int v[4]; int s = 0;
#pragma unroll
    for (int i = 0; i < 4; i++) {
        int idx = t * 4 + i;
        v[i] = (idx < NCH) ? cntmat[roff + idx] : 0;
        s += v[i];
    }
    int incl = scan256(s, sh, t);
    int ex = incl - s;
#pragma unroll
    for (int i = 0; i < 4; i++) {
        int idx = t * 4 + i;
        if (idx < NCH) pre[roff + idx] = ex;
        ex += v[i];
    }
    if (t == 255) tot[g] = incl;
}

// ---------------------------------------------------------------------------
// Finalize: per bucket, gather the bucket's per-chunk slices from chunkbuf
// into LDS (placement via pre — no atomics), then LDS hist+scan -> row_ptr
// and scatter src into eidx (bucket-local, L2-combined).
// ---------------------------------------------------------------------------
__global__ __launch_bounds__(256) void csr_finalize_kernel(
    const int2* __restrict__ chunkbuf,
    const int* __restrict__ cntmat, const int* __restrict__ ofsmat,
    const int* __restrict__ pre, const int* __restrict__ tot,
    int* __restrict__ row_ptr, int* __restrict__ eidx)
{
    __shared__ int sh[256];
    __shared__ int basel[512];
    __shared__ int cnt[512];
    __shared__ int excl[512];
    __shared__ int2 rec[CAP_REC];
    const int t = threadIdx.x;
    const int g = blockIdx.x;
    const int l0 = 2 * t, l1 = 2 * t + 1;

    build_base(tot, basel, sh, t);
    cnt[l0] = 0; cnt[l1] = 0;
    __syncthreads();

    const int b0 = basel[g];
    const int b1 = basel[g + 1];
    const int Eloc = b1 - b0;
    const int segbase = g << SEG_SHIFT;
    const bool fits = (Eloc <= CAP_REC);   // block-uniform

    if (fits) {
        // gather slices into LDS at pre-determined positions
        for (int c = t; c < NCH; c += 256) {
            size_t m = (size_t)g * NCH + c;
            int len = cntmat[m];
            int off = ofsmat[m];
            int dst = pre[m];
            for (int i = 0; i < len; i++)
                rec[dst + i] = chunkbuf[c * CH + off + i];
        }
        __syncthreads();
        for (int i = t; i < Eloc; i += 256)
            atomicAdd(&cnt[rec[i].y - segbase], 1);       // LDS atomic
    } else {
        // fallback: hist directly from chunkbuf slices
        for (int c = t; c < NCH; c += 256) {
            size_t m = (size_t)g * NCH + c;
            int len = cntmat[m];
            int off = ofsmat[m];
            for (int i = 0; i < len; i++) {
                int2 r = chunkbuf[c * CH + off + i];
                atomicAdd(&cnt[r.y - segbase], 1);
            }
        }
    }
    __syncthreads();

    int c0 = cnt[l0], c1 = cnt[l1];
    int ssum = c0 + c1;
    int inc2 = scan256(ssum, sh, t);
    int ex2 = inc2 - ssum;
    excl[l0] = ex2;
    excl[l1] = ex2 + c0;
    __syncthreads();

    int nloc = NSEG_TOT - segbase;
    if (nloc > 512) nloc = 512;
    for (int l = t; l < nloc; l += 256) row_ptr[segbase + l] = b0 + excl[l];
    if (g == 0 && t == 0) row_ptr[NSEG_TOT] = ETOT;

    cnt[l0] = 0; cnt[l1] = 0;                            // cursors
    __syncthreads();

    if (fits) {
        for (int i = t; i < Eloc; i += 256) {
            int2 r = rec[i];
            int l = r.y - segbase;
            int rk = atomicAdd(&cnt[l], 1);
            eidx[b0 + excl[l] + rk] = r.x;               // bucket-local, L2-combined
        }
    } else {
        for (int c = t; c < NCH; c += 256) {
            size_t m = (size_t)g * NCH + c;
            int len = cntmat[m];
            int off = ofsmat[m];
            for (int i = 0; i < len; i++) {
                int2 r = chunkbuf[c * CH + off + i];
                int l = r.y - segbase;
                int rk = atomicAdd(&cnt[l], 1);
                eidx[b0 + excl[l] + rk] = r.x;
            }
        }
    }
}

// ---------------------------------------------------------------------------
// Aggregation: one wave per CSR segment. 8 B/lane loads -> 2 neighbor rows
// per wave-iteration (half-waves), cross-half shfl_xor reduce at the end.
// ---------------------------------------------------------------------------
__global__ __launch_bounds__(256) void aggregate_kernel(
    const __hip_bfloat16* __restrict__ xb,
    const int* __restrict__ row_ptr,
    const int* __restrict__ eidx,
    __hip_bfloat16* __restrict__ hn,
    int nseg)
{
    int wid = (blockIdx.x * 256 + threadIdx.x) >> 6;
    const int lane = threadIdx.x & 63;
    if (wid >= nseg) return;
    wid = __builtin_amdgcn_readfirstlane(wid);

    const int beg = row_ptr[wid];
    const int end = row_ptr[wid + 1];
    const int cnt = end - beg;
    const int half = lane >> 5;
    const int l32 = lane & 31;

    float4 s = make_float4(0.f, 0.f, 0.f, 0.f);
    int k = beg;
    for (; k + 4 <= end; k += 4) {
        int i0 = eidx[k + 0];
        int i1 = eidx[k + 1];
        int i2 = eidx[k + 2];
        int i3 = eidx[k + 3];
        int ra = half ? i1 : i0;
        int rb = half ? i3 : i2;
        float4 va = ld4bf(xb + (long)ra * DD + l32 * 4);
        float4 vb = ld4bf(xb + (long)rb * DD + l32 * 4);
        s.x += va.x + vb.x; s.y += va.y + vb.y;
        s.z += va.z + vb.z; s.w += va.w + vb.w;
    }
    if (k + 2 <= end) {
        int i0 = eidx[k];
        int i1 = eidx[k + 1];
        int r = half ? i1 : i0;
        float4 v = ld4bf(xb + (long)r * DD + l32 * 4);
        s.x += v.x; s.y += v.y; s.z += v.z; s.w += v.w;
        k += 2;
    }
    if (k < end && !half) {
        int i0 = eidx[k];
        float4 v = ld4bf(xb + (long)i0 * DD + l32 * 4);
        s.x += v.x; s.y += v.y; s.z += v.z; s.w += v.w;
    }

    s.x += __shfl_xor(s.x, 32);
    s.y += __shfl_xor(s.y, 32);
    s.z += __shfl_xor(s.z, 32);
    s.w += __shfl_xor(s.w, 32);

    if (!half) {
        const float inv = 1.f / (float)(cnt > 1 ? cnt : 1);
        float4 m = make_float4(s.x * inv, s.y * inv, s.z * inv, s.w * inv);
        st4bf(hn + (long)wid * DD + l32 * 4, m);
    }
}

// ---------------------------------------------------------------------------
// MFMA combine: D[outcol][node] = Wc^T (A-op) x Xcat^T (B-op), K=384.
// ---------------------------------------------------------------------------
template <bool RELU, typename TOUT>
__global__ __launch_bounds__(256) void mfma_combine_kernel(
    const __hip_bfloat16* __restrict__ xself,   // [M][128] bf16
    const __hip_bfloat16* __restrict__ hn,      // [2*M][128] bf16
    const short* __restrict__ wfrag,            // 12*8*64*8 bf16 bits
    const float* __restrict__ b0, const float* __restrict__ b1,
    TOUT* __restrict__ out, int M)
{
    const int t = threadIdx.x;
    const int wave = t >> 6;
    const int lane = t & 63;
    const int nsub = lane & 15;
    const int quad = lane >> 4;
    const int base = blockIdx.x * 128 + wave * 32;

    const int node0 = base + nsub;
    const int node1 = base + 16 + nsub;
    const long n0c = node0 < M ? node0 : M - 1;
    const long n1c = node1 < M ? node1 : M - 1;

    floatx4 acc[2][8];
#pragma unroll
    for (int nt = 0; nt < 2; nt++)
#pragma unroll
        for (int mt = 0; mt < 8; mt++) acc[nt][mt] = (floatx4){0.f, 0.f, 0.f, 0.f};

    for (int kc = 0; kc < 12; kc++) {
        const __hip_bfloat16* src;
        long r0, r1;
        int koff;
        if (kc < 4)      { src = xself; koff = kc * 32;       r0 = n0c;     r1 = n1c; }
        else if (kc < 8) { src = hn;    koff = (kc - 4) * 32; r0 = n0c;     r1 = n1c; }
        else             { src = hn;    koff = (kc - 8) * 32; r0 = M + n0c; r1 = M + n1c; }

        short8 bf0 = *(const short8*)(src + r0 * DD + koff + quad * 8);
        short8 bf1 = *(const short8*)(src + r1 * DD + koff + quad * 8);
        const short* wbase = wfrag + ((size_t)(kc * 8) * 64 + lane) * 8;
#pragma unroll
        for (int mt = 0; mt < 8; mt++) {
            short8 af = *(const short8*)(wbase + (size_t)mt * 64 * 8);
            acc[0][mt] = __builtin_amdgcn_mfma_f32_16x16x32_bf16(af, bf0, acc[0][mt], 0, 0, 0);
            acc[1][mt] = __builtin_amdgcn_mfma_f32_16x16x32_bf16(af, bf1, acc[1][mt], 0, 0, 0);
        }
    }

#pragma unroll
    for (int nt = 0; nt < 2; nt++) {
        int node = (nt == 0) ? node0 : node1;
        if (node >= M) continue;
#pragma unroll
        for (int mt = 0; mt < 8; mt++) {
            int c0 = mt * 16 + quad * 4;
            float4 bb0 = *(const float4*)(b0 + c0);
            float4 bb1 = *(const float4*)(b1 + c0);
            float v0 = acc[nt][mt][0] + bb0.x + bb1.x;
            float v1 = acc[nt][mt][1] + bb0.y + bb1.y;
            float v2 = acc[nt][mt][2] + bb0.z + bb1.z;
            float v3 = acc[nt][mt][3] + bb0.w + bb1.w;
            if (RELU) {
                v0 = v0 > 0.f ? v0 : 0.f;
                v1 = v1 > 0.f ? v1 : 0.f;
                v2 = v2 > 0.f ? v2 : 0.f;
                v3 = v3 > 0.f ? v3 : 0.f;
            }
            TOUT* p = out + (long)node * DD + c0;
            if constexpr (sizeof(TOUT) == 4) {
                *(float4*)p = make_float4(v0, v1, v2, v3);
            } else {
                short vs[4];
                vs[0] = bf16bits(v0); vs[1] = bf16bits(v1);
                vs[2] = bf16bits(v2); vs[3] = bf16bits(v3);
                *(int2*)p = *(int2*)vs;
            }
        }
    }
}

// ---------------------------------------------------------------------------

extern "C" void kernel_launch(void* const* d_in, const int* in_sizes, int n_in,
                              void* d_out, int out_size, void* d_ws, size_t ws_size,
                              hipStream_t stream)
{
    const float* x = (const float*)d_in[0];
    const int* e0_src_r0 = (const int*)d_in[1];
    const int* e0_dst_r0 = (const int*)d_in[2];
    const int* e0_src_r1 = (const int*)d_in[3];
    const int* e0_dst_r1 = (const int*)d_in[4];
    const int* e1_src_r0 = (const int*)d_in[5];
    const int* e1_dst_r0 = (const int*)d_in[6];
    const int* e1_src_r1 = (const int*)d_in[7];
    const int* e1_dst_r1 = (const int*)d_in[8];
    const float* Ws1_r0 = (const float*)d_in[9];
    const float* Wn1_r0 = (const float*)d_in[10];
    const float* Ws1_r1 = (const float*)d_in[11];
    const float* Wn1_r1 = (const float*)d_in[12];
    const float* Ws2_r0 = (const float*)d_in[13];
    const float* Wn2_r0 = (const float*)d_in[14];
    const float* Ws2_r1 = (const float*)d_in[15];
    const float* Wn2_r1 = (const float*)d_in[16];
    const float* b1_r0 = (const float*)d_in[17];
    const float* b1_r1 = (const float*)d_in[18];
    const float* b2_r0 = (const float*)d_in[19];
    const float* b2_r1 = (const float*)d_in[20];
    float* out = (float*)d_out;

    // Workspace (~62.1 MB; aliases proven in R5-R7):
    //   xb       : N0*DD bf16 (25.6 MB); h1 aliases xb (row-for-row WAR-safe)
    //   hn       : 2*N1*DD bf16 (25.6 MB); chunkbuf (ETOT int2, 14.4 MB)
    //              aliases hn (chunkbuf dead before agg1 writes hn)
    //   eidx     : ETOT int (7.2 MB)
    //   row_ptr  : NSEG_TOT+4 int
    //   cntmat/ofsmat/pre : 3 x NBK*NCH int (2.9 MB)
    //   tot      : NBK+4 int
    //   wfrag1/2 : 2 x 49152 bf16 (192 KB)
    __hip_bfloat16* xb = (__hip_bfloat16*)d_ws;
    __hip_bfloat16* h1 = xb;
    __hip_bfloat16* hn = xb + (size_t)N0 * DD;
    int2* chunkbuf = (int2*)hn;
    int* eidx     = (int*)(hn + (size_t)2 * N1 * DD);
    int* row_ptr  = eidx + ETOT;
    int* cntmat   = row_ptr + NSEG_TOT + 4;
    int* ofsmat   = cntmat + NBK * NCH;
    int* pre      = ofsmat + NBK * NCH;
    int* tot      = pre + NBK * NCH;
    short* wfrag1 = (short*)(tot + NBK + 4);
    short* wfrag2 = wfrag1 + 12 * 8 * 64 * 8;

    // 1. prologue: cast + weight-prep + chunk-local bucket sort
    prologue_kernel<<<PROLOGUE_BLOCKS, 256, 0, stream>>>(
        x, xb,
        e0_src_r0, e0_dst_r0, e0_src_r1, e0_dst_r1,
        e1_src_r0, e1_dst_r0, e1_src_r1, e1_dst_r1,
        cntmat, ofsmat, chunkbuf,
        Ws1_r0, Ws1_r1, Wn1_r0, Wn1_r1,
        Ws2_r0, Ws2_r1, Wn2_r0, Wn2_r1,
        wfrag1, wfrag2);

    // 2. per-bucket scan across chunks
    scan_chunks_kernel<<<NBK, 256, 0, stream>>>(cntmat, pre, tot);

    // 3. per-bucket CSR finalize (slices -> LDS -> row_ptr + eidx)
    csr_finalize_kernel<<<NBK, 256, 0, stream>>>(
        chunkbuf, cntmat, ofsmat, pre, tot, row_ptr, eidx);

    // 4-5. layer 1
    aggregate_kernel<<<(2 * N1 + 3) / 4, 256, 0, stream>>>(xb, row_ptr, eidx, hn, 2 * N1);
    mfma_combine_kernel<true, __hip_bfloat16>
        <<<(N1 + 127) / 128, 256, 0, stream>>>(xb, hn, wfrag1, b1_r0, b1_r1, h1, N1);

    // 6-7. layer 2
    aggregate_kernel<<<(2 * N2 + 3) / 4, 256, 0, stream>>>(h1, row_ptr + 2 * N1, eidx, hn, 2 * N2);
    mfma_combine_kernel<false, float>
        <<<(N2 + 127) / 128, 256, 0, stream>>>(h1, hn, wfrag2, b2_r0, b2_r1, out, N2);
}

// Round 10
// 273.629 us; speedup vs baseline: 3.0264x; 1.0339x over previous
//
#include <hip/hip_runtime.h>
#include <hip/hip_bf16.h>
#include <hip/hip_fp8.h>

#define N0 100000
#define N1 50000
#define N2 20000
#define DD 128
#define E0 600000
#define E1 300000

#define NSEG_TOT (2 * N1 + 2 * N2)              // 140000 concat CSR segments
#define ETOT     (2 * E0 + 2 * E1)              // 1800000 edges

// counting-sort geometry
#define SEG_SHIFT 9                              // 512 segments per bucket
#define NBK  ((NSEG_TOT + 511) / 512)            // 274 buckets
#define CH   2048                                // edges per chunk
#define NCH  ((ETOT + CH - 1) / CH)              // 879 chunks
#define PADCAP 8192                              // eidx slots per bucket (mean 6582, +20 sigma)

#define CAST_BLOCKS 6250                         // N0*DD/8 / 256
#define PREP_BLOCKS 48                           // 2*6144/256
#define PROLOGUE_BLOCKS (CAST_BLOCKS + PREP_BLOCKS + NCH)

typedef __attribute__((ext_vector_type(8))) short short8;   // 8 bf16 (4 VGPRs)
typedef __attribute__((ext_vector_type(4))) float floatx4;  // MFMA acc

__device__ __forceinline__ void st2bf(__hip_bfloat16* p, float a, float b) {
    __hip_bfloat162 v;
    v.x = __float2bfloat16(a);
    v.y = __float2bfloat16(b);
    *(__hip_bfloat162*)p = v;
}
__device__ __forceinline__ short bf16bits(float v) {
    __hip_bfloat16 b = __float2bfloat16(v);
    return *(short*)&b;
}
__device__ __forceinline__ float bf2f(unsigned short u) {
    return __uint_as_float(((unsigned int)u) << 16);
}
__device__ __forceinline__ float4 ld4bf(const __hip_bfloat16* p) {  // 8B load
    ushort4 u = *(const ushort4*)p;
    return make_float4(bf2f(u.x), bf2f(u.y), bf2f(u.z), bf2f(u.w));
}
__device__ __forceinline__ void st4bf(__hip_bfloat16* p, float4 v) { // 8B store
    short vs[4];
    vs[0] = bf16bits(v.x); vs[1] = bf16bits(v.y);
    vs[2] = bf16bits(v.z); vs[3] = bf16bits(v.w);
    *(int2*)p = *(int2*)vs;
}
__device__ __forceinline__ unsigned char f8enc(float f) {
    __hip_fp8_e4m3 v(f);
    return (unsigned char)v.__x;
}
__device__ __forceinline__ float f8dec(unsigned char b) {
    __hip_fp8_e4m3 v;
    v.__x = (__hip_fp8_storage_t)b;
    return (float)v;
}

// inclusive Hillis-Steele scan over 256 threads; every thread must call.
// After return, sh[255] holds the total (valid until sh is overwritten).
__device__ __forceinline__ int scan256(int s, int* sh, int t) {
    sh[t] = s;
    __syncthreads();
    for (int off = 1; off < 256; off <<= 1) {
        int tmp = (t >= off) ? sh[t - off] : 0;
        __syncthreads();
        sh[t] += tmp;
        __syncthreads();
    }
    return sh[t];
}

// Edge mapping for the concatenated CSR (4 edge lists)
__device__ __forceinline__ int2 edge_seg_src(int e,
    const int* s0, const int* d0, const int* s1, const int* d1,
    const int* s2, const int* d2, const int* s3, const int* d3)
{
    if (e < E0)               return make_int2(s0[e],            d0[e]);
    if (e < 2 * E0)           return make_int2(s1[e - E0],       N1 + d1[e - E0]);
    if (e < 2 * E0 + E1)      return make_int2(s2[e - 2 * E0],   2 * N1 + d2[e - 2 * E0]);
    int ee = e - 2 * E0 - E1;
    return make_int2(s3[ee], 2 * N1 + N2 + d3[ee]);
}

// ---------------------------------------------------------------------------
// Prologue: [cast | weight-prep | chunk-local bucket sort], by blockIdx range.
// Cast writes BOTH bf16 table (self-frags / h1 home) and fp8 gather table.
// Chunk part: LDS hist -> LDS scan -> LDS scatter -> coalesced packed write.
// Packed record: src (17 bits) | segLow (9 bits) << 17.
// ---------------------------------------------------------------------------
__global__ __launch_bounds__(256) void prologue_kernel(
    const float* __restrict__ x, __hip_bfloat16* __restrict__ xb,
    unsigned char* __restrict__ xf8,
    const int* __restrict__ s0a, const int* __restrict__ d0a,
    const int* __restrict__ s0b, const int* __restrict__ d0b,
    const int* __restrict__ s1a, const int* __restrict__ d1a,
    const int* __restrict__ s1b, const int* __restrict__ d1b,
    int* __restrict__ cntmat, int* __restrict__ ofsmat,
    unsigned* __restrict__ chunkbuf,
    const float* __restrict__ Ws1a, const float* __restrict__ Ws1b,
    const float* __restrict__ Wn1a, const float* __restrict__ Wn1b,
    const float* __restrict__ Ws2a, const float* __restrict__ Ws2b,
    const float* __restrict__ Wn2a, const float* __restrict__ Wn2b,
    short* __restrict__ wfrag1, short* __restrict__ wfrag2)
{
    __shared__ int hist[512];
    __shared__ int ofs[512];
    __shared__ int sh[256];
    __shared__ unsigned rec[CH];
    const int bid = blockIdx.x;
    const int t = threadIdx.x;

    if (bid < CAST_BLOCKS) {
        int i = bid * 256 + t;                          // 8-elem group, < 1.6M exactly
        const float4* xp = (const float4*)x + (size_t)i * 2;
        float4 a = xp[0], b = xp[1];
        __hip_bfloat16* pb = xb + (size_t)i * 8;
        st2bf(pb + 0, a.x, a.y); st2bf(pb + 2, a.z, a.w);
        st2bf(pb + 4, b.x, b.y); st2bf(pb + 6, b.z, b.w);
        unsigned long long w = 0;
        w |= (unsigned long long)f8enc(a.x);
        w |= (unsigned long long)f8enc(a.y) << 8;
        w |= (unsigned long long)f8enc(a.z) << 16;
        w |= (unsigned long long)f8enc(a.w) << 24;
        w |= (unsigned long long)f8enc(b.x) << 32;
        w |= (unsigned long long)f8enc(b.y) << 40;
        w |= (unsigned long long)f8enc(b.z) << 48;
        w |= (unsigned long long)f8enc(b.w) << 56;
        *(unsigned long long*)(xf8 + (size_t)i * 8) = w;
    } else if (bid < CAST_BLOCKS + PREP_BLOCKS) {
        int p = (bid - CAST_BLOCKS) * 256 + t;          // < 12288
        int layer = p >= 6144;
        int q = p - layer * 6144;
        int lane = q & 63;
        int mt = (q >> 6) & 7;
        int kc = q >> 9;
        int n = mt * 16 + (lane & 15);
        int k0 = kc * 32 + ((lane >> 4) << 3);
        const float* Wsa = layer ? Ws2a : Ws1a;
        const float* Wsb = layer ? Ws2b : Ws1b;
        const float* Wna = layer ? Wn2a : Wn1a;
        const float* Wnb = layer ? Wn2b : Wn1b;
        short* wf = layer ? wfrag2 : wfrag1;
        short vals[8];
#pragma unroll
        for (int j = 0; j < 8; j++) {
            int k = k0 + j;
            float w;
            if (k < 128)      w = Wsa[k * DD + n] + Wsb[k * DD + n];
            else if (k < 256) w = Wna[(k - 128) * DD + n];
            else              w = Wnb[(k - 256) * DD + n];
            vals[j] = bf16bits(w);
        }
        *(short8*)(wf + (size_t)q * 8) = *(short8*)vals;
    } else {
        const int chunk = bid - CAST_BLOCKS - PREP_BLOCKS;
        const int ebase = chunk * CH;
        const int ecount = (ETOT - ebase < CH) ? (ETOT - ebase) : CH;

        hist[t] = 0; hist[t + 256] = 0;
        __syncthreads();

        int2 myrec[CH / 256];
#pragma unroll
        for (int it = 0; it < CH / 256; it++) {
            int e = ebase + it * 256 + t;
            int2 r = make_int2(0, -1);
            if (e < ETOT) {
                r = edge_seg_src(e, s0a, d0a, s0b, d0b, s1a, d1a, s1b, d1b);
                atomicAdd(&hist[r.y >> SEG_SHIFT], 1);   // LDS atomic
            }
            myrec[it] = r;
        }
        __syncthreads();

        // exclusive scan over 512 bucket slots (2/thread)
        const int l0 = 2 * t, l1 = 2 * t + 1;
        int c0 = hist[l0], c1 = hist[l1];
        int s = c0 + c1;
        int incl = scan256(s, sh, t);
        int ex = incl - s;
        ofs[l0] = ex;
        ofs[l1] = ex + c0;
        __syncthreads();

        // write per-chunk counts and offsets (before cursors mutate ofs)
        for (int g = t; g < NBK; g += 256) {
            cntmat[(size_t)g * NCH + chunk] = hist[g];
            ofsmat[(size_t)g * NCH + chunk] = ofs[g];
        }
        __syncthreads();

        // scatter packed records into bucket order in LDS (ofs now cursors)
#pragma unroll
        for (int it = 0; it < CH / 256; it++) {
            int2 r = myrec[it];
            if (r.y >= 0) {
                int rk = atomicAdd(&ofs[r.y >> SEG_SHIFT], 1);  // LDS atomic
                rec[rk] = (unsigned)r.x | ((unsigned)(r.y & 511) << 17);
            }
        }
        __syncthreads();

        for (int i = t; i < ecount; i += 256)
            chunkbuf[ebase + i] = rec[i];
    }
}

// ---------------------------------------------------------------------------
// Finalize: block g scans its OWN cntmat row (no cross-bucket state), gathers
// its chunk slices into LDS at scan positions, LDS hist+scan -> row_beg/cnt,
// then scatters srcs into the bucket's padded eidx region (L2-local).
// ---------------------------------------------------------------------------
__global__ __launch_bounds__(256) void csr_finalize_kernel(
    const unsigned* __restrict__ chunkbuf,
    const int* __restrict__ cntmat, const int* __restrict__ ofsmat,
    int* __restrict__ row_beg, int* __restrict__ row_cnt,
    int* __restrict__ eidx)
{
    __shared__ int sh[256];
    __shared__ int preL[NCH];
    __shared__ int lenL[NCH];
    __shared__ int cnt[512];
    __shared__ int excl[512];
    __shared__ unsigned rec[PADCAP];
    const int t = threadIdx.x;
    const int g = blockIdx.x;
    const int l0 = 2 * t, l1 = 2 * t + 1;

    // 1. scan own cntmat row -> preL (exclusive), lenL
    int v[4]; int s = 0;
#pragma unroll
    for (int i = 0; i < 4; i++) {
        int idx = t * 4 + i;
        v[i] = (idx < NCH) ? cntmat[(size_t)g * NCH + idx] : 0;
        s += v[i];
    }
    int incl = scan256(s, sh, t);
    int ex = incl - s;
#pragma unroll
    for (int i = 0; i < 4; i++) {
        int idx = t * 4 + i;
        if (idx < NCH) { preL[idx] = ex; lenL[idx] = v[i]; }
        ex += v[i];
    }
    int Eloc = sh[255];
    if (Eloc > PADCAP) Eloc = PADCAP;     // statistically impossible; safety clamp
    cnt[l0] = 0; cnt[l1] = 0;
    __syncthreads();

    // 2. gather slices into rec at scan positions (no atomics)
    for (int c = t; c < NCH; c += 256) {
        int len = lenL[c];
        int dst = preL[c];
        int off = ofsmat[(size_t)g * NCH + c];
        const unsigned* src = chunkbuf + (size_t)c * CH + off;
        for (int i = 0; i < len; i++) rec[dst + i] = src[i];
    }
    __syncthreads();

    // 3. per-segment hist
    for (int i = t; i < Eloc; i += 256)
        atomicAdd(&cnt[rec[i] >> 17], 1);                 // LDS atomic
    __syncthreads();

    // 4. scan 512 segment counts -> excl
    int c0 = cnt[l0], c1 = cnt[l1];
    int ssum = c0 + c1;
    int inc2 = scan256(ssum, sh, t);
    int ex2 = inc2 - ssum;
    excl[l0] = ex2;
    excl[l1] = ex2 + c0;
    __syncthreads();

    // 5. write row_beg / row_cnt, then reset cnt as cursors
    const int segbase = g << SEG_SHIFT;
    const int base = g * PADCAP;
    int nloc = NSEG_TOT - segbase;
    if (nloc > 512) nloc = 512;
    for (int l = t; l < nloc; l += 256) {
        row_beg[segbase + l] = base + excl[l];
        row_cnt[segbase + l] = cnt[l];
    }
    __syncthreads();
    cnt[l0] = 0; cnt[l1] = 0;
    __syncthreads();

    // 6. scatter srcs into padded eidx region (32 KB span -> L2 write-combined)
    for (int i = t; i < Eloc; i += 256) {
        unsigned r = rec[i];
        int l = r >> 17;
        int pos = atomicAdd(&cnt[l], 1);
        eidx[base + excl[l] + pos] = (int)(r & 0x1FFFF);
    }
}

// ---------------------------------------------------------------------------
// Layer-1 aggregation from fp8 table: one wave per segment; quarter-waves
// (16 lanes x 8 B = one 128-B row) -> 4 rows per load-iteration, unroll x2.
// Cross-quarter shfl_xor(16,32) reduce; lanes 0..15 store the bf16 mean row.
// ---------------------------------------------------------------------------
__global__ __launch_bounds__(256) void aggregate_fp8_kernel(
    const unsigned char* __restrict__ xf8,
    const int* __restrict__ row_beg, const int* __restrict__ row_cnt,
    const int* __restrict__ eidx,
    __hip_bfloat16* __restrict__ hn,
    int nseg)
{
    int wid = (blockIdx.x * 256 + threadIdx.x) >> 6;
    const int lane = threadIdx.x & 63;
    if (wid >= nseg) return;
    wid = __builtin_amdgcn_readfirstlane(wid);

    const int beg = row_beg[wid];
    const int cnt = row_cnt[wid];
    const int end = beg + cnt;
    const int q = lane >> 4;
    const int l16 = lane & 15;

    float acc[8];
#pragma unroll
    for (int j = 0; j < 8; j++) acc[j] = 0.f;

    int k = beg;
    for (; k + 8 <= end; k += 8) {
        int iA = eidx[k + q];
        int iB = eidx[k + 4 + q];
        unsigned long long a = *(const unsigned long long*)(xf8 + (size_t)iA * DD + l16 * 8);
        unsigned long long b = *(const unsigned long long*)(xf8 + (size_t)iB * DD + l16 * 8);
#pragma unroll
        for (int j = 0; j < 8; j++) {
            acc[j] += f8dec((unsigned char)(a >> (8 * j)));
            acc[j] += f8dec((unsigned char)(b >> (8 * j)));
        }
    }
    if (k + 4 <= end) {
        int iA = eidx[k + q];
        unsigned long long a = *(const unsigned long long*)(xf8 + (size_t)iA * DD + l16 * 8);
#pragma unroll
        for (int j = 0; j < 8; j++) acc[j] += f8dec((unsigned char)(a >> (8 * j)));
        k += 4;
    }
    int rem = end - k;
    if (q < rem) {
        int iA = eidx[k + q];
        unsigned long long a = *(const unsigned long long*)(xf8 + (size_t)iA * DD + l16 * 8);
#pragma unroll
        for (int j = 0; j < 8; j++) acc[j] += f8dec((unsigned char)(a >> (8 * j)));
    }

#pragma unroll
    for (int j = 0; j < 8; j++) {
        acc[j] += __shfl_xor(acc[j], 16);
        acc[j] += __shfl_xor(acc[j], 32);
    }

    if (lane < 16) {
        const float inv = 1.f / (float)(cnt > 1 ? cnt : 1);
        short vs[8];
#pragma unroll
        for (int j = 0; j < 8; j++) vs[j] = bf16bits(acc[j] * inv);
        *(int4*)(hn + (size_t)wid * DD + l16 * 8) = *(int4*)vs;
    }
}

// ---------------------------------------------------------------------------
// Layer-2 aggregation (bf16 table, as R9): half-waves, 2 rows per iteration.
// ---------------------------------------------------------------------------
__global__ __launch_bounds__(256) void aggregate_kernel(
    const __hip_bfloat16* __restrict__ xb,
    const int* __restrict__ row_beg, const int* __restrict__ row_cnt,
    const int* __restrict__ eidx,
    __hip_bfloat16* __restrict__ hn,
    int nseg)
{
    int wid = (blockIdx.x * 256 + threadIdx.x) >> 6;
    const int lane = threadIdx.x & 63;
    if (wid >= nseg) return;
    wid = __builtin_amdgcn_readfirstlane(wid);

    const int beg = row_beg[wid];
    const int cnt = row_cnt[wid];
    const int end = beg + cnt;
    const int half = lane >> 5;
    const int l32 = lane & 31;

    float4 s = make_float4(0.f, 0.f, 0.f, 0.f);
    int k = beg;
    for (; k + 4 <= end; k += 4) {
        int i0 = eidx[k + 0];
        int i1 = eidx[k + 1];
        int i2 = eidx[k + 2];
        int i3 = eidx[k + 3];
        int ra = half ? i1 : i0;
        int rb = half ? i3 : i2;
        float4 va = ld4bf(xb + (long)ra * DD + l32 * 4);
        float4 vb = ld4bf(xb + (long)rb * DD + l32 * 4);
        s.x += va.x + vb.x; s.y += va.y + vb.y;
        s.z += va.z + vb.z; s.w += va.w + vb.w;
    }
    if (k + 2 <= end) {
        int i0 = eidx[k];
        int i1 = eidx[k + 1];
        int r = half ? i1 : i0;
        float4 v = ld4bf(xb + (long)r * DD + l32 * 4);
        s.x += v.x; s.y += v.y; s.z += v.z; s.w += v.w;
        k += 2;
    }
    if (k < end && !half) {
        int i0 = eidx[k];
        float4 v = ld4bf(xb + (long)i0 * DD + l32 * 4);
        s.x += v.x; s.y += v.y; s.z += v.z; s.w += v.w;
    }

    s.x += __shfl_xor(s.x, 32);
    s.y += __shfl_xor(s.y, 32);
    s.z += __shfl_xor(s.z, 32);
    s.w += __shfl_xor(s.w, 32);

    if (!half) {
        const float inv = 1.f / (float)(cnt > 1 ? cnt : 1);
        float4 m = make_float4(s.x * inv, s.y * inv, s.z * inv, s.w * inv);
        st4bf(hn + (long)wid * DD + l32 * 4, m);
    }
}

// ---------------------------------------------------------------------------
// MFMA combine: D[outcol][node] = Wc^T (A-op) x Xcat^T (B-op), K=384.
// ---------------------------------------------------------------------------
template <bool RELU, typename TOUT>
__global__ __launch_bounds__(256) void mfma_combine_kernel(
    const __hip_bfloat16* __restrict__ xself,   // [M][128] bf16
    const __hip_bfloat16* __restrict__ hn,      // [2*M][128] bf16
    const short* __restrict__ wfrag,            // 12*8*64*8 bf16 bits
    const float* __restrict__ b0, const float* __restrict__ b1,
    TOUT* __restrict__ out, int M)
{
    const int t = threadIdx.x;
    const int wave = t >> 6;
    const int lane = t & 63;
    const int nsub = lane & 15;
    const int quad = lane >> 4;
    const int base = blockIdx.x * 128 + wave * 32;

    const int node0 = base + nsub;
    const int node1 = base + 16 + nsub;
    const long n0c = node0 < M ? node0 : M - 1;
    const long n1c = node1 < M ? node1 : M - 1;

    floatx4 acc[2][8];
#pragma unroll
    for (int nt = 0; nt < 2; nt++)
#pragma unroll
        for (int mt = 0; mt < 8; mt++) acc[nt][mt] = (floatx4){0.f, 0.f, 0.f, 0.f};

    for (int kc = 0; kc < 12; kc++) {
        const __hip_bfloat16* src;
        long r0, r1;
        int koff;
        if (kc < 4)      { src = xself; koff = kc * 32;       r0 = n0c;     r1 = n1c; }
        else if (kc < 8) { src = hn;    koff = (kc - 4) * 32; r0 = n0c;     r1 = n1c; }
        else             { src = hn;    koff = (kc - 8) * 32; r0 = M + n0c; r1 = M + n1c; }

        short8 bf0 = *(const short8*)(src + r0 * DD + koff + quad * 8);
        short8 bf1 = *(const short8*)(src + r1 * DD + koff + quad * 8);
        const short* wbase = wfrag + ((size_t)(kc * 8) * 64 + lane) * 8;
#pragma unroll
        for (int mt = 0; mt < 8; mt++) {
            short8 af = *(const short8*)(wbase + (size_t)mt * 64 * 8);
            acc[0][mt] = __builtin_amdgcn_mfma_f32_16x16x32_bf16(af, bf0, acc[0][mt], 0, 0, 0);
            acc[1][mt] = __builtin_amdgcn_mfma_f32_16x16x32_bf16(af, bf1, acc[1][mt], 0, 0, 0);
        }
    }

#pragma unroll
    for (int nt = 0; nt < 2; nt++) {
        int node = (nt == 0) ? node0 : node1;
        if (node >= M) continue;
#pragma unroll
        for (int mt = 0; mt < 8; mt++) {
            int c0 = mt * 16 + quad * 4;
            float4 bb0 = *(const float4*)(b0 + c0);
            float4 bb1 = *(const float4*)(b1 + c0);
            float v0 = acc[nt][mt][0] + bb0.x + bb1.x;
            float v1 = acc[nt][mt][1] + bb0.y + bb1.y;
            float v2 = acc[nt][mt][2] + bb0.z + bb1.z;
            float v3 = acc[nt][mt][3] + bb0.w + bb1.w;
            if (RELU) {
                v0 = v0 > 0.f ? v0 : 0.f;
                v1 = v1 > 0.f ? v1 : 0.f;
                v2 = v2 > 0.f ? v2 : 0.f;
                v3 = v3 > 0.f ? v3 : 0.f;
            }
            TOUT* p = out + (long)node * DD + c0;
            if constexpr (sizeof(TOUT) == 4) {
                *(float4*)p = make_float4(v0, v1, v2, v3);
            } else {
                short vs[4];
                vs[0] = bf16bits(v0); vs[1] = bf16bits(v1);
                vs[2] = bf16bits(v2); vs[3] = bf16bits(v3);
                *(int2*)p = *(int2*)vs;
            }
        }
    }
}

// ---------------------------------------------------------------------------

extern "C" void kernel_launch(void* const* d_in, const int* in_sizes, int n_in,
                              void* d_out, int out_size, void* d_ws, size_t ws_size,
                              hipStream_t stream)
{
    const float* x = (const float*)d_in[0];
    const int* e0_src_r0 = (const int*)d_in[1];
    const int* e0_dst_r0 = (const int*)d_in[2];
    const int* e0_src_r1 = (const int*)d_in[3];
    const int* e0_dst_r1 = (const int*)d_in[4];
    const int* e1_src_r0 = (const int*)d_in[5];
    const int* e1_dst_r0 = (const int*)d_in[6];
    const int* e1_src_r1 = (const int*)d_in[7];
    const int* e1_dst_r1 = (const int*)d_in[8];
    const float* Ws1_r0 = (const float*)d_in[9];
    const float* Wn1_r0 = (const float*)d_in[10];
    const float* Ws1_r1 = (const float*)d_in[11];
    const float* Wn1_r1 = (const float*)d_in[12];
    const float* Ws2_r0 = (const float*)d_in[13];
    const float* Wn2_r0 = (const float*)d_in[14];
    const float* Ws2_r1 = (const float*)d_in[15];
    const float* Wn2_r1 = (const float*)d_in[16];
    const float* b1_r0 = (const float*)d_in[17];
    const float* b1_r1 = (const float*)d_in[18];
    const float* b2_r0 = (const float*)d_in[19];
    const float* b2_r1 = (const float*)d_in[20];
    float* out = (float*)d_out;

    // Workspace (~76 MB; R1 ran ~98 MB of ws without faulting):
    //   xb      : N0*DD bf16 (25.6 MB); h1 aliases xb (row-for-row WAR-safe:
    //             combine1 reads xb row then writes h1 to same row)
    //   xf8     : N0*DD fp8 (12.8 MB) — layer-1 gather table only
    //   hn      : 2*N1*DD bf16 (25.6 MB); chunkbuf (ETOT uint, 7.2 MB)
    //             aliases hn (dead before agg1 writes hn)
    //   eidx    : NBK*PADCAP int (9.0 MB, padded per-bucket regions)
    //   row_beg/row_cnt : NSEG_TOT int each (1.12 MB)
    //   cntmat/ofsmat   : NBK*NCH int each (1.93 MB)
    //   wfrag1/2: 192 KB
    __hip_bfloat16* xb = (__hip_bfloat16*)d_ws;
    __hip_bfloat16* h1 = xb;
    unsigned char* xf8 = (unsigned char*)(xb + (size_t)N0 * DD);
    __hip_bfloat16* hn = (__hip_bfloat16*)(xf8 + (size_t)N0 * DD);
    unsigned* chunkbuf = (unsigned*)hn;
    int* eidx     = (int*)(hn + (size_t)2 * N1 * DD);
    int* row_beg  = eidx + NBK * PADCAP;
    int* row_cnt  = row_beg + NSEG_TOT;
    int* cntmat   = row_cnt + NSEG_TOT;
    int* ofsmat   = cntmat + NBK * NCH;
    short* wfrag1 = (short*)(ofsmat + NBK * NCH);
    short* wfrag2 = wfrag1 + 12 * 8 * 64 * 8;

    // 1. prologue: cast (bf16 + fp8) + weight-prep + chunk-local bucket sort
    prologue_kernel<<<PROLOGUE_BLOCKS, 256, 0, stream>>>(
        x, xb, xf8,
        e0_src_r0, e0_dst_r0, e0_src_r1, e0_dst_r1,
        e1_src_r0, e1_dst_r0, e1_src_r1, e1_dst_r1,
        cntmat, ofsmat, chunkbuf,
        Ws1_r0, Ws1_r1, Wn1_r0, Wn1_r1,
        Ws2_r0, Ws2_r1, Wn2_r0, Wn2_r1,
        wfrag1, wfrag2);

    // 2. per-bucket finalize (own-row scan -> gather -> row_beg/cnt + eidx)
    csr_finalize_kernel<<<NBK, 256, 0, stream>>>(
        chunkbuf, cntmat, ofsmat, row_beg, row_cnt, eidx);

    // 3-4. layer 1
    aggregate_fp8_kernel<<<(2 * N1 + 3) / 4, 256, 0, stream>>>(
        xf8, row_beg, row_cnt, eidx, hn, 2 * N1);
    mfma_combine_kernel<true, __hip_bfloat16>
        <<<(N1 + 127) / 128, 256, 0, stream>>>(xb, hn, wfrag1, b1_r0, b1_r1, h1, N1);

    // 5-6. layer 2
    aggregate_kernel<<<(2 * N2 + 3) / 4, 256, 0, stream>>>(
        h1, row_beg + 2 * N1, row_cnt + 2 * N1, eidx, hn, 2 * N2);
    mfma_combine_kernel<false, float>
        <<<(N2 + 127) / 128, 256, 0, stream>>>(h1, hn, wfrag2, b2_r0, b2_r1, out, N2);
}